// Round 7
// baseline (1494.902 us; speedup 1.0000x reference)
//
#include <hip/hip_runtime.h>
#include <hip/hip_bf16.h>
#include <hip/hip_cooperative_groups.h>
#include <math.h>

namespace cg = cooperative_groups;

// Problem constants (fixed by the reference)
#define NNODES 10000
#define NEDGES 320000
#define FIN    500
#define HIDN   64
#define NC     10
#define RANKP  3
#define KHOP   10
#define KP1    11       // K+1 Chebyshev terms
#define CBLKS  512      // cooperative grid: 2 blocks/CU x 256 CUs (launch_bounds(256,2))
#define NGRP   (CBLKS * 16)   // 8192 16-lane groups grid-wide

// ---------------------------------------------------------------------------
// Graph norm. PROOF (R0, verified passing R1/R3): w_off[e] = -dinv[src]*dinv[dst]
// <= 0 for every edge, so lam = 2*max(max(w_off),1) == 2.0 always => rescale
// identity, diag == 0. prop() is a pure edge gather with weight -dinv_s*dinv_d.
// ---------------------------------------------------------------------------

// deg[src] += 1 (for dinv), cnt[dst] += 1 (for CSR), self-loops excluded.
__global__ void degcnt_kernel(const int* __restrict__ src, const int* __restrict__ dst,
                              float* __restrict__ deg, int* __restrict__ cnt) {
  int e = blockIdx.x * 256 + threadIdx.x;
  if (e >= NEDGES) return;
  int s = src[e], d = dst[e];
  if (s != d) {
    atomicAdd(&deg[s], 1.0f);
    atomicAdd(&cnt[d], 1);
  }
}

// Exclusive scan of cnt[0..N) -> row_start[0..N], plus cursor copy.
// Single block, 256 threads x 40-element chunks (L2-hot; proven in R3).
__global__ __launch_bounds__(256) void scan_kernel(const int* __restrict__ cnt,
                                                   int* __restrict__ row_start,
                                                   int* __restrict__ cursor) {
  const int t = threadIdx.x, lane = t & 63, w = t >> 6;
  const int CH = 40;                     // 256*40 = 10240 >= NNODES
  const int base = t * CH;
  int sum = 0;
  for (int j = 0; j < CH; ++j) {
    int idx = base + j;
    if (idx < NNODES) sum += cnt[idx];
  }
  int inc = sum;                         // wave-level inclusive scan
#pragma unroll
  for (int d = 1; d < 64; d <<= 1) {
    int u = __shfl_up(inc, d);
    if (lane >= d) inc += u;
  }
  __shared__ int wtot[4];
  if (lane == 63) wtot[w] = inc;
  __syncthreads();
  int add = 0;
  for (int i = 0; i < 4; ++i)
    if (i < w) add += wtot[i];
  int run = add + inc - sum;             // exclusive prefix for this chunk
  for (int j = 0; j < CH; ++j) {
    int idx = base + j;
    if (idx < NNODES) {
      int v = cnt[idx];
      row_start[idx] = run;
      cursor[idx] = run;
      run += v;
    }
  }
  if (t == 255) row_start[NNODES] = run;
}

// CSR fill with dinv folded in: packed[slot] = (src, -dinv_s*dinv_d), by dst.
__global__ void fill_kernel(const int* __restrict__ src, const int* __restrict__ dst,
                            const float* __restrict__ deg, int* __restrict__ cursor,
                            int2* __restrict__ packed) {
  int e = blockIdx.x * 256 + threadIdx.x;
  if (e >= NEDGES) return;
  int s = src[e], d = dst[e];
  if (s == d) return;
  float ds_ = deg[s], dd = deg[d];
  float dis = (ds_ > 0.f) ? 1.0f / sqrtf(ds_) : 0.f;
  float did = (dd  > 0.f) ? 1.0f / sqrtf(dd)  : 0.f;
  float w = -dis * did;
  int slot = atomicAdd(&cursor[d], 1);
  packed[slot] = make_int2(s, __float_as_int(w));
}

// ---------------------------------------------------------------------------
// Cooperative mega-kernel: MLP -> 10 Chebyshev props -> proj, with grid.sync()
// between phases. 512 blocks x 256 threads; each block owns 16 nodes per pass
// (16-lane group per node), node stride NGRP=8192 covers N=10000 in 2 passes.
// ---------------------------------------------------------------------------
__global__ __launch_bounds__(256, 2) void coop_kernel(
    const float* __restrict__ feature, const float* __restrict__ W1,
    const float* __restrict__ b1, const float* __restrict__ W2,
    const float* __restrict__ b2, const int* __restrict__ row_start,
    const int2* __restrict__ packed, const float* __restrict__ Wp,
    const float* __restrict__ bp, const float* __restrict__ gamma,
    float* __restrict__ Txall, float* __restrict__ Emat) {
  cg::grid_group grid = cg::this_grid();
  const int t = threadIdx.x;
  const int b = blockIdx.x;

  // ---- Phase 0: MLP  Tx0 = relu(feat@W1+b1)@W2+b2 ----
  __shared__ float hid[16][HIDN + 1];    // +1 pad: no bank conflict in layer-2
  {
    const int w = t >> 6, lane = t & 63;
    for (int pass = 0; pass < 2; ++pass) {
      const int base = pass * NGRP + b * 16;
      for (int nn = w * 4; nn < w * 4 + 4; ++nn) {   // each wave: 4 nodes
        const int node = base + nn;
        float acc0 = b1[lane], acc1 = 0.f;
        if (node < NNODES) {
          const float* frow = feature + (size_t)node * FIN;
          for (int f = 0; f < FIN; f += 2) {          // split dep chain
            acc0 = fmaf(frow[f],     W1[f * HIDN + lane],       acc0);
            acc1 = fmaf(frow[f + 1], W1[(f + 1) * HIDN + lane], acc1);
          }
        }
        hid[nn][lane] = fmaxf(acc0 + acc1, 0.f);
      }
      __syncthreads();
      if (t < 16 * NC) {
        const int nn = t / NC, c = t - nn * NC;
        const int node = base + nn;
        if (node < NNODES) {
          float a2 = b2[c];
#pragma unroll
          for (int k2 = 0; k2 < HIDN; ++k2)
            a2 = fmaf(hid[nn][k2], W2[k2 * NC + c], a2);
          Txall[(size_t)node * NC + c] = a2;
        }
      }
      __syncthreads();
    }
  }
  grid.sync();

  // ---- Phases 1..10: Tx_s = scale*P(Tx_{s-1}) - Tx_{s-2} ----
  const int grp = t >> 4, lane16 = t & 15;
  const int gid = b * 16 + grp;          // 16-lane group id, 0..NGRP-1
  for (int step = 1; step <= KHOP; ++step) {
    const float* tin  = Txall + (size_t)(step - 1) * NNODES * NC;
    const float* sub  = (step >= 2) ? Txall + (size_t)(step - 2) * NNODES * NC
                                    : nullptr;
    float*       tout = Txall + (size_t)step * NNODES * NC;
    const float scale = (step >= 2) ? 2.f : 1.f;
    for (int node = gid; node < NNODES; node += NGRP) {
      const int s0 = row_start[node], s1 = row_start[node + 1];
      float acc[NC];
#pragma unroll
      for (int c = 0; c < NC; ++c) acc[c] = 0.f;
      for (int j = s0 + lane16; j < s1; j += 16) {
        int2 p = packed[j];
        float w = __int_as_float(p.y);
        const float2* t2 = (const float2*)(tin + (size_t)p.x * NC);
        float2 a0 = t2[0], a1 = t2[1], a2 = t2[2], a3 = t2[3], a4 = t2[4];
        acc[0] = fmaf(w, a0.x, acc[0]); acc[1] = fmaf(w, a0.y, acc[1]);
        acc[2] = fmaf(w, a1.x, acc[2]); acc[3] = fmaf(w, a1.y, acc[3]);
        acc[4] = fmaf(w, a2.x, acc[4]); acc[5] = fmaf(w, a2.y, acc[5]);
        acc[6] = fmaf(w, a3.x, acc[6]); acc[7] = fmaf(w, a3.y, acc[7]);
        acc[8] = fmaf(w, a4.x, acc[8]); acc[9] = fmaf(w, a4.y, acc[9]);
      }
#pragma unroll
      for (int c = 0; c < NC; ++c) {     // reduce within 16-lane group
        float v = acc[c];
#pragma unroll
        for (int off = 8; off > 0; off >>= 1) v += __shfl_xor(v, off);
        acc[c] = v;
      }
      if (lane16 == 0) {
        float* to = tout + (size_t)node * NC;
        if (sub) {
          const float* sb = sub + (size_t)node * NC;
#pragma unroll
          for (int c = 0; c < NC; ++c) to[c] = fmaf(scale, acc[c], -sb[c]);
        } else {
#pragma unroll
          for (int c = 0; c < NC; ++c) to[c] = acc[c];
        }
      }
    }
    grid.sync();
  }

  // ---- Phase 11: proj  Emat[k][i] = (tanh(Tx_k[i]@Wp[k]+bp[k])@gamma[:,k])/3
  {
    const int idx = b * 256 + t;         // 131072 threads >= N*KP1 = 110000
    if (idx < NNODES * KP1) {
      const int k = idx / NNODES, i = idx - k * NNODES;
      const float* tx = Txall + ((size_t)k * NNODES + i) * NC;
      float tv[NC];
#pragma unroll
      for (int c = 0; c < NC; ++c) tv[c] = tx[c];
      float e = 0.f;
#pragma unroll
      for (int r = 0; r < RANKP; ++r) {
        float hh = bp[k * RANKP + r];
#pragma unroll
        for (int c = 0; c < NC; ++c)
          hh = fmaf(tv[c], Wp[(k * NC + c) * RANKP + r], hh);
        e = fmaf(tanhf(hh), gamma[r * KP1 + k], e);
      }
      Emat[(size_t)k * NNODES + i] = e * (1.0f / RANKP);
    }
  }
}

// ---------------------------------------------------------------------------
// etam(N,11) = CTC(N,N) @ E^T, fused with the final weighted-sum + log_softmax.
// 4 rows/block; reads CTC exactly once (400 MB -> the HBM-bound dispatch).
// ---------------------------------------------------------------------------
__global__ __launch_bounds__(256) void gemv_final_kernel(
    const float* __restrict__ CTC, const float* __restrict__ Emat,
    const float* __restrict__ Txall, float* __restrict__ out) {
  const int i0 = blockIdx.x * 4;
  const int t = threadIdx.x;
  float acc[4][KP1];
#pragma unroll
  for (int r = 0; r < 4; ++r)
#pragma unroll
    for (int k = 0; k < KP1; ++k) acc[r][k] = 0.f;

  const int n4 = NNODES / 4;  // 2500 float4 per row
  for (int j4 = t; j4 < n4; j4 += 256) {
    float4 ev[KP1];
#pragma unroll
    for (int k = 0; k < KP1; ++k)
      ev[k] = ((const float4*)(Emat + (size_t)k * NNODES))[j4];
#pragma unroll
    for (int r = 0; r < 4; ++r) {
      float4 cv = ((const float4*)(CTC + (size_t)(i0 + r) * NNODES))[j4];
#pragma unroll
      for (int k = 0; k < KP1; ++k) {
        acc[r][k] = fmaf(cv.x, ev[k].x, acc[r][k]);
        acc[r][k] = fmaf(cv.y, ev[k].y, acc[r][k]);
        acc[r][k] = fmaf(cv.z, ev[k].z, acc[r][k]);
        acc[r][k] = fmaf(cv.w, ev[k].w, acc[r][k]);
      }
    }
  }

#pragma unroll
  for (int r = 0; r < 4; ++r)
#pragma unroll
    for (int k = 0; k < KP1; ++k) {
      float v = acc[r][k];
#pragma unroll
      for (int off = 32; off > 0; off >>= 1) v += __shfl_xor(v, off);
      acc[r][k] = v;
    }
  __shared__ float red[4][4 * KP1];
  const int w = t >> 6, lane = t & 63;
  if (lane == 0) {
#pragma unroll
    for (int r = 0; r < 4; ++r)
#pragma unroll
      for (int k = 0; k < KP1; ++k) red[w][r * KP1 + k] = acc[r][k];
  }
  __syncthreads();
  if (t < 4 * KP1) {                     // cross-wave sum -> etam in red[0][*]
    red[0][t] = red[0][t] + red[1][t] + red[2][t] + red[3][t];
  }
  __syncthreads();
  if (t < 4) {                           // fused final: per-node log_softmax
    const int node = i0 + t;
    float h[NC];
#pragma unroll
    for (int c = 0; c < NC; ++c) h[c] = 0.f;
    for (int k = 0; k < KP1; ++k) {
      const float e = red[0][t * KP1 + k];
      const float* tx = Txall + ((size_t)k * NNODES + node) * NC;
#pragma unroll
      for (int c = 0; c < NC; ++c) h[c] = fmaf(tx[c], e, h[c]);
    }
    float m = h[0];
#pragma unroll
    for (int c = 1; c < NC; ++c) m = fmaxf(m, h[c]);
    float s = 0.f;
#pragma unroll
    for (int c = 0; c < NC; ++c) s += expf(h[c] - m);
    const float ls = logf(s);
#pragma unroll
    for (int c = 0; c < NC; ++c) out[(size_t)node * NC + c] = h[c] - m - ls;
  }
}

// ---------------------------------------------------------------------------
extern "C" void kernel_launch(void* const* d_in, const int* in_sizes, int n_in,
                              void* d_out, int out_size, void* d_ws, size_t ws_size,
                              hipStream_t stream) {
  const float* feature = (const float*)d_in[0];
  const int*   edges   = (const int*)d_in[1];   // verified R3: int32 (passed)
  const float* CTC     = (const float*)d_in[2];
  const float* W1      = (const float*)d_in[3];
  const float* b1      = (const float*)d_in[4];
  const float* W2      = (const float*)d_in[5];
  const float* b2      = (const float*)d_in[6];
  const float* gamma   = (const float*)d_in[7];
  const float* Wp      = (const float*)d_in[8];
  const float* bp      = (const float*)d_in[9];
  const int* src = edges;
  const int* dst = edges + NEDGES;
  float* out = (float*)d_out;

  // workspace carve-up (~9 MB; d_ws is 0xAA-poisoned before every call)
  float* ws        = (float*)d_ws;
  float* Txall     = ws;                                    // KP1*N*NC floats
  float* deg       = Txall + (size_t)KP1 * NNODES * NC;     // N floats
  int*   cnt       = (int*)(deg + NNODES);                  // N ints (zeroed w/ deg)
  int*   row_start = cnt + NNODES;                          // N+1 ints
  int*   cursor    = row_start + NNODES + 8;                // N ints
  int2*  packed    = (int2*)(cursor + NNODES + 8);          // E int2 (8B-aligned)
  float* Emat      = (float*)(packed + NEDGES);             // KP1*N floats

  const int EB = (NEDGES + 255) / 256;

  // zero deg (N floats) + cnt (N ints) in one memset — contiguous by layout
  hipMemsetAsync(deg, 0, 2 * NNODES * sizeof(float), stream);

  degcnt_kernel<<<EB, 256, 0, stream>>>(src, dst, deg, cnt);
  scan_kernel<<<1, 256, 0, stream>>>(cnt, row_start, cursor);
  fill_kernel<<<EB, 256, 0, stream>>>(src, dst, deg, cursor, packed);

  void* cargs[] = {(void*)&feature, (void*)&W1, (void*)&b1, (void*)&W2,
                   (void*)&b2, (void*)&row_start, (void*)&packed, (void*)&Wp,
                   (void*)&bp, (void*)&gamma, (void*)&Txall, (void*)&Emat};
  hipLaunchCooperativeKernel((const void*)coop_kernel, dim3(CBLKS), dim3(256),
                             cargs, 0, stream);

  gemv_final_kernel<<<NNODES / 4, 256, 0, stream>>>(CTC, Emat, Txall, out);
}

// Round 10
// 798.118 us; speedup vs baseline: 1.8730x; 1.8730x over previous
//
#include <hip/hip_runtime.h>
#include <hip/hip_bf16.h>
#include <math.h>

// Problem constants (fixed by the reference)
#define NNODES 10000
#define NEDGES 320000
#define FIN    500
#define HIDN   64
#define NC     10
#define RANKP  3
#define KHOP   10
#define KP1    11   // K+1 Chebyshev terms

// ---------------------------------------------------------------------------
// MLP: x = relu(feature @ W1 + b1) @ W2 + b2 -> Tx0 (N,10). R1-proven version:
// 4 nodes/block, one wave per node, features staged in LDS (coalesced).
// ---------------------------------------------------------------------------
__global__ __launch_bounds__(256) void mlp_kernel(
    const float* __restrict__ feature, const float* __restrict__ W1,
    const float* __restrict__ b1, const float* __restrict__ W2,
    const float* __restrict__ b2, float* __restrict__ Tx0) {
  __shared__ float feat[4][FIN];
  __shared__ float hid[4][HIDN];
  const int t = threadIdx.x;
  const int n = t >> 6;      // wave id == local node
  const int h = t & 63;
  const int i0 = blockIdx.x * 4;

  for (int idx = t; idx < 4 * FIN; idx += 256) {
    int nn = idx / FIN, f = idx - nn * FIN;
    feat[nn][f] = feature[(size_t)(i0 + nn) * FIN + f];
  }
  __syncthreads();

  float acc = b1[h];
#pragma unroll 4
  for (int f = 0; f < FIN; ++f)
    acc = fmaf(feat[n][f], W1[f * HIDN + h], acc);
  hid[n][h] = fmaxf(acc, 0.f);
  __syncthreads();

  if (h < NC) {
    float a2 = b2[h];
#pragma unroll
    for (int k = 0; k < HIDN; ++k)
      a2 = fmaf(hid[n][k], W2[k * NC + h], a2);
    Tx0[(size_t)(i0 + n) * NC + h] = a2;
  }
}

// ---------------------------------------------------------------------------
// Graph norm. PROOF (R0, verified passing R1/R3/R7): w_off[e] =
// -dinv[src]*dinv[dst] <= 0 for every edge, so lam = 2*max(max(w_off),1) == 2.0
// always => rescale identity, diag == 0. prop() is a pure edge gather.
// LESSON (R7, counter-backed): grid.sync() ~65us on MI355X (8 XCDs, spin via
// device-scope flag) -> use separate kernel launches (~4us) as phase syncs.
// ---------------------------------------------------------------------------

// deg[src] += 1 (for dinv), cnt[dst] += 1 (for CSR), self-loops excluded.
__global__ void degcnt_kernel(const int* __restrict__ src, const int* __restrict__ dst,
                              float* __restrict__ deg, int* __restrict__ cnt) {
  int e = blockIdx.x * 256 + threadIdx.x;
  if (e >= NEDGES) return;
  int s = src[e], d = dst[e];
  if (s != d) {
    atomicAdd(&deg[s], 1.0f);
    atomicAdd(&cnt[d], 1);
  }
}

// Exclusive scan of cnt[0..N) -> row_start[0..N], plus cursor copy.
// Single block, 256 threads x 40-element chunks (L2-hot; proven R3/R7).
__global__ __launch_bounds__(256) void scan_kernel(const int* __restrict__ cnt,
                                                   int* __restrict__ row_start,
                                                   int* __restrict__ cursor) {
  const int t = threadIdx.x, lane = t & 63, w = t >> 6;
  const int CH = 40;                     // 256*40 = 10240 >= NNODES
  const int base = t * CH;
  int sum = 0;
  for (int j = 0; j < CH; ++j) {
    int idx = base + j;
    if (idx < NNODES) sum += cnt[idx];
  }
  int inc = sum;                         // wave-level inclusive scan
#pragma unroll
  for (int d = 1; d < 64; d <<= 1) {
    int u = __shfl_up(inc, d);
    if (lane >= d) inc += u;
  }
  __shared__ int wtot[4];
  if (lane == 63) wtot[w] = inc;
  __syncthreads();
  int add = 0;
  for (int i = 0; i < 4; ++i)
    if (i < w) add += wtot[i];
  int run = add + inc - sum;             // exclusive prefix for this chunk
  for (int j = 0; j < CH; ++j) {
    int idx = base + j;
    if (idx < NNODES) {
      int v = cnt[idx];
      row_start[idx] = run;
      cursor[idx] = run;
      run += v;
    }
  }
  if (t == 255) row_start[NNODES] = run;
}

// CSR fill with dinv folded in: packed[slot] = (src, -dinv_s*dinv_d), by dst.
__global__ void fill_kernel(const int* __restrict__ src, const int* __restrict__ dst,
                            const float* __restrict__ deg, int* __restrict__ cursor,
                            int2* __restrict__ packed) {
  int e = blockIdx.x * 256 + threadIdx.x;
  if (e >= NEDGES) return;
  int s = src[e], d = dst[e];
  if (s == d) return;
  float ds_ = deg[s], dd = deg[d];
  float dis = (ds_ > 0.f) ? 1.0f / sqrtf(ds_) : 0.f;
  float did = (dd  > 0.f) ? 1.0f / sqrtf(dd)  : 0.f;
  float w = -dis * did;
  int slot = atomicAdd(&cursor[d], 1);
  packed[slot] = make_int2(s, __float_as_int(w));
}

// ---------------------------------------------------------------------------
// Gather prop (atomic-free): one 16-lane group per node (mean in-degree 32).
//   tout[i,:] = scale * sum_{in-edges} w_e * tin[src_e,:]  - sub[i,:]
// sub==nullptr for Tx1 = P(Tx0); else fused Chebyshev Tx2 = 2*P(Tx1) - Tx0.
// ---------------------------------------------------------------------------
__global__ __launch_bounds__(256) void gather_kernel(
    const int* __restrict__ row_start, const int2* __restrict__ packed,
    const float* __restrict__ tin, const float* __restrict__ sub,
    float* __restrict__ tout, float scale) {
  const int g    = (blockIdx.x * 256 + threadIdx.x) >> 4;  // node id
  const int lane = threadIdx.x & 15;
  if (g >= NNODES) return;
  const int s0 = row_start[g], s1 = row_start[g + 1];
  float acc[NC];
#pragma unroll
  for (int c = 0; c < NC; ++c) acc[c] = 0.f;
  for (int j = s0 + lane; j < s1; j += 16) {
    int2 p = packed[j];
    float w = __int_as_float(p.y);
    const float2* t2 = (const float2*)(tin + (size_t)p.x * NC);  // 8B-aligned
    float2 a0 = t2[0], a1 = t2[1], a2 = t2[2], a3 = t2[3], a4 = t2[4];
    acc[0] = fmaf(w, a0.x, acc[0]); acc[1] = fmaf(w, a0.y, acc[1]);
    acc[2] = fmaf(w, a1.x, acc[2]); acc[3] = fmaf(w, a1.y, acc[3]);
    acc[4] = fmaf(w, a2.x, acc[4]); acc[5] = fmaf(w, a2.y, acc[5]);
    acc[6] = fmaf(w, a3.x, acc[6]); acc[7] = fmaf(w, a3.y, acc[7]);
    acc[8] = fmaf(w, a4.x, acc[8]); acc[9] = fmaf(w, a4.y, acc[9]);
  }
#pragma unroll
  for (int c = 0; c < NC; ++c) {       // reduce within the 16-lane group
    float v = acc[c];
#pragma unroll
    for (int off = 8; off > 0; off >>= 1) v += __shfl_xor(v, off);
    acc[c] = v;
  }
  if (lane == 0) {
    float* to = tout + (size_t)g * NC;
    if (sub) {
      const float* sb = sub + (size_t)g * NC;
#pragma unroll
      for (int c = 0; c < NC; ++c) to[c] = fmaf(scale, acc[c], -sb[c]);
    } else {
#pragma unroll
      for (int c = 0; c < NC; ++c) to[c] = scale * acc[c];
    }
  }
}

// ---------------------------------------------------------------------------
// e_k[i] = (tanh(Tx_k[i] @ Wp[k] + bp[k]) @ gamma[:,k]) / RANK, one thread per
// (k,i); Emat layout (KP1, N) so the gemv can float4-load each e_k row.
// ---------------------------------------------------------------------------
__global__ void proj_kernel(const float* __restrict__ Txall, const float* __restrict__ Wp,
                            const float* __restrict__ bp, const float* __restrict__ gamma,
                            float* __restrict__ Emat) {
  int idx = blockIdx.x * 256 + threadIdx.x;
  if (idx >= NNODES * KP1) return;
  const int k = idx / NNODES, i = idx - k * NNODES;
  const float* tx = Txall + ((size_t)k * NNODES + i) * NC;
  float tv[NC];
#pragma unroll
  for (int c = 0; c < NC; ++c) tv[c] = tx[c];
  float e = 0.f;
#pragma unroll
  for (int r = 0; r < RANKP; ++r) {
    float hh = bp[k * RANKP + r];
#pragma unroll
    for (int c = 0; c < NC; ++c)
      hh = fmaf(tv[c], Wp[(k * NC + c) * RANKP + r], hh);
    e = fmaf(tanhf(hh), gamma[r * KP1 + k], e);
  }
  Emat[(size_t)k * NNODES + i] = e * (1.0f / RANKP);
}

// ---------------------------------------------------------------------------
// etam(N,11) = CTC(N,N) @ E^T fused with final weighted-sum + log_softmax.
// 4 rows/block; reads CTC exactly once (400 MB -> the HBM-bound dispatch).
// Verified passing as part of R7.
// ---------------------------------------------------------------------------
__global__ __launch_bounds__(256) void gemv_final_kernel(
    const float* __restrict__ CTC, const float* __restrict__ Emat,
    const float* __restrict__ Txall, float* __restrict__ out) {
  const int i0 = blockIdx.x * 4;
  const int t = threadIdx.x;
  float acc[4][KP1];
#pragma unroll
  for (int r = 0; r < 4; ++r)
#pragma unroll
    for (int k = 0; k < KP1; ++k) acc[r][k] = 0.f;

  const int n4 = NNODES / 4;  // 2500 float4 per row
  for (int j4 = t; j4 < n4; j4 += 256) {
    float4 ev[KP1];
#pragma unroll
    for (int k = 0; k < KP1; ++k)
      ev[k] = ((const float4*)(Emat + (size_t)k * NNODES))[j4];
#pragma unroll
    for (int r = 0; r < 4; ++r) {
      float4 cv = ((const float4*)(CTC + (size_t)(i0 + r) * NNODES))[j4];
#pragma unroll
      for (int k = 0; k < KP1; ++k) {
        acc[r][k] = fmaf(cv.x, ev[k].x, acc[r][k]);
        acc[r][k] = fmaf(cv.y, ev[k].y, acc[r][k]);
        acc[r][k] = fmaf(cv.z, ev[k].z, acc[r][k]);
        acc[r][k] = fmaf(cv.w, ev[k].w, acc[r][k]);
      }
    }
  }

#pragma unroll
  for (int r = 0; r < 4; ++r)
#pragma unroll
    for (int k = 0; k < KP1; ++k) {
      float v = acc[r][k];
#pragma unroll
      for (int off = 32; off > 0; off >>= 1) v += __shfl_xor(v, off);
      acc[r][k] = v;
    }
  __shared__ float red[4][4 * KP1];
  const int w = t >> 6, lane = t & 63;
  if (lane == 0) {
#pragma unroll
    for (int r = 0; r < 4; ++r)
#pragma unroll
      for (int k = 0; k < KP1; ++k) red[w][r * KP1 + k] = acc[r][k];
  }
  __syncthreads();
  if (t < 4 * KP1) {                   // cross-wave sum -> etam in red[0][*]
    red[0][t] = red[0][t] + red[1][t] + red[2][t] + red[3][t];
  }
  __syncthreads();
  if (t < 4) {                         // fused final: per-node log_softmax
    const int node = i0 + t;
    float h[NC];
#pragma unroll
    for (int c = 0; c < NC; ++c) h[c] = 0.f;
    for (int k = 0; k < KP1; ++k) {
      const float e = red[0][t * KP1 + k];
      const float* tx = Txall + ((size_t)k * NNODES + node) * NC;
#pragma unroll
      for (int c = 0; c < NC; ++c) h[c] = fmaf(tx[c], e, h[c]);
    }
    float m = h[0];
#pragma unroll
    for (int c = 1; c < NC; ++c) m = fmaxf(m, h[c]);
    float s = 0.f;
#pragma unroll
    for (int c = 0; c < NC; ++c) s += expf(h[c] - m);
    const float ls = logf(s);
#pragma unroll
    for (int c = 0; c < NC; ++c) out[(size_t)node * NC + c] = h[c] - m - ls;
  }
}

// ---------------------------------------------------------------------------
extern "C" void kernel_launch(void* const* d_in, const int* in_sizes, int n_in,
                              void* d_out, int out_size, void* d_ws, size_t ws_size,
                              hipStream_t stream) {
  const float* feature = (const float*)d_in[0];
  const int*   edges   = (const int*)d_in[1];   // verified R3/R7: int32
  const float* CTC     = (const float*)d_in[2];
  const float* W1      = (const float*)d_in[3];
  const float* b1      = (const float*)d_in[4];
  const float* W2      = (const float*)d_in[5];
  const float* b2      = (const float*)d_in[6];
  const float* gamma   = (const float*)d_in[7];
  const float* Wp      = (const float*)d_in[8];
  const float* bp      = (const float*)d_in[9];
  const int* src = edges;
  const int* dst = edges + NEDGES;
  float* out = (float*)d_out;

  // workspace carve-up (~9 MB; d_ws is 0xAA-poisoned before every call)
  float* ws        = (float*)d_ws;
  float* Txall     = ws;                                    // KP1*N*NC floats
  float* deg       = Txall + (size_t)KP1 * NNODES * NC;     // N floats
  int*   cnt       = (int*)(deg + NNODES);                  // N ints (zeroed w/ deg)
  int*   row_start = cnt + NNODES;                          // N+1 ints
  int*   cursor    = row_start + NNODES + 8;                // N ints
  int2*  packed    = (int2*)(cursor + NNODES + 8);          // E int2 (8B-aligned)
  float* Emat      = (float*)(packed + NEDGES);             // KP1*N floats

  const int EB = (NEDGES + 255) / 256;
  const int GB = (NNODES * 16 + 255) / 256;       // 16-lane-group grids
  const int PB = (NNODES * KP1 + 255) / 256;      // proj grid

  // zero deg (N floats) + cnt (N ints) in one memset — contiguous by layout
  hipMemsetAsync(deg, 0, 2 * NNODES * sizeof(float), stream);

  mlp_kernel<<<NNODES / 4, 256, 0, stream>>>(feature, W1, b1, W2, b2, Txall);
  degcnt_kernel<<<EB, 256, 0, stream>>>(src, dst, deg, cnt);
  scan_kernel<<<1, 256, 0, stream>>>(cnt, row_start, cursor);
  fill_kernel<<<EB, 256, 0, stream>>>(src, dst, deg, cursor, packed);

  // Tx1 = P(Tx0); then Tx_{k+1} = 2*P(Tx_k) - Tx_{k-1}  (all atomic-free)
  float* Tx0 = Txall;
  float* Tx1 = Txall + (size_t)NNODES * NC;
  gather_kernel<<<GB, 256, 0, stream>>>(row_start, packed, Tx0, nullptr, Tx1, 1.0f);
  for (int k = 1; k < KHOP; ++k) {
    float* prev = Txall + (size_t)(k - 1) * NNODES * NC;
    float* cur  = Txall + (size_t)k * NNODES * NC;
    float* nxt  = Txall + (size_t)(k + 1) * NNODES * NC;
    gather_kernel<<<GB, 256, 0, stream>>>(row_start, packed, cur, prev, nxt, 2.0f);
  }

  proj_kernel<<<PB, 256, 0, stream>>>(Txall, Wp, bp, gamma, Emat);
  gemv_final_kernel<<<NNODES / 4, 256, 0, stream>>>(CTC, Emat, Txall, out);
}

// Round 12
// 755.397 us; speedup vs baseline: 1.9790x; 1.0566x over previous
//
#include <hip/hip_runtime.h>
#include <hip/hip_bf16.h>
#include <math.h>

// Problem constants (fixed by the reference)
#define NNODES 10000
#define NEDGES 320000
#define FIN    500
#define HIDN   64
#define NC     10
#define RANKP  3
#define KHOP   10
#define KP1    11   // K+1 Chebyshev terms
#define MLPB   (NNODES / 8)   // 1250 MLP blocks (8 nodes each)
#define EB     (NEDGES / 256) // 1250 edge blocks (exact)

// ---------------------------------------------------------------------------
// Fused kernel A: blocks [0,MLPB) run the MLP (8 nodes/block, float4-staged
// LDS); blocks [MLPB, MLPB+EB) run degcnt. Independent work, one dispatch.
// PROOF (R0, verified R1/R3/R7/R10): w_off[e] = -dinv_s*dinv_d <= 0 for all
// edges => lam == 2.0 always => rescale identity, diag == 0.
// LESSON (R7, counter-backed): grid.sync ~65us on MI355X -> kernel-boundary
// syncs (~4us) instead; independent phases fused by block-range split.
// ---------------------------------------------------------------------------
__global__ __launch_bounds__(256) void mlp_degcnt_kernel(
    const float* __restrict__ feature, const float* __restrict__ W1,
    const float* __restrict__ b1, const float* __restrict__ W2,
    const float* __restrict__ b2, const int* __restrict__ src,
    const int* __restrict__ dst, float* __restrict__ Tx0,
    float* __restrict__ deg, int* __restrict__ cnt) {
  __shared__ float feat[8][FIN];
  __shared__ float hid[8][HIDN + 1];
  const int t = threadIdx.x;
  if (blockIdx.x < MLPB) {
    // ---- MLP: Tx0 = relu(feat@W1+b1)@W2+b2 ----
    const int i0 = blockIdx.x * 8;
    // stage 8 contiguous feature rows as 1000 float4 (rows are contiguous)
    const float4* fsrc = (const float4*)(feature + (size_t)i0 * FIN);
    float4* fdst = (float4*)&feat[0][0];
    for (int j = t; j < (8 * FIN) / 4; j += 256) fdst[j] = fsrc[j];
    __syncthreads();
    const int w = t >> 6, lane = t & 63;
    for (int nn = w; nn < 8; nn += 4) {       // each wave: 2 nodes
      float acc0 = b1[lane], acc1 = 0.f;
      for (int f = 0; f < FIN; f += 2) {      // split dep chain (FIN even)
        acc0 = fmaf(feat[nn][f],     W1[f * HIDN + lane],       acc0);
        acc1 = fmaf(feat[nn][f + 1], W1[(f + 1) * HIDN + lane], acc1);
      }
      hid[nn][lane] = fmaxf(acc0 + acc1, 0.f);
    }
    __syncthreads();
    if (t < 8 * NC) {
      const int nn = t / NC, c = t - nn * NC;
      float a2 = b2[c];
#pragma unroll
      for (int k2 = 0; k2 < HIDN; ++k2)
        a2 = fmaf(hid[nn][k2], W2[k2 * NC + c], a2);
      Tx0[(size_t)(i0 + nn) * NC + c] = a2;
    }
  } else {
    // ---- degcnt: deg[src]+=1, cnt[dst]+=1 (self-loops excluded) ----
    int e = (blockIdx.x - MLPB) * 256 + t;
    if (e < NEDGES) {
      int s = src[e], d = dst[e];
      if (s != d) {
        atomicAdd(&deg[s], 1.0f);
        atomicAdd(&cnt[d], 1);
      }
    }
  }
}

// Exclusive scan of cnt[0..N) -> row_start[0..N], plus cursor copy.
// Single block, 256 threads x 40-element chunks (L2-hot; proven R3/R7/R10).
__global__ __launch_bounds__(256) void scan_kernel(const int* __restrict__ cnt,
                                                   int* __restrict__ row_start,
                                                   int* __restrict__ cursor) {
  const int t = threadIdx.x, lane = t & 63, w = t >> 6;
  const int CH = 40;                     // 256*40 = 10240 >= NNODES
  const int base = t * CH;
  int sum = 0;
  for (int j = 0; j < CH; ++j) {
    int idx = base + j;
    if (idx < NNODES) sum += cnt[idx];
  }
  int inc = sum;                         // wave-level inclusive scan
#pragma unroll
  for (int d = 1; d < 64; d <<= 1) {
    int u = __shfl_up(inc, d);
    if (lane >= d) inc += u;
  }
  __shared__ int wtot[4];
  if (lane == 63) wtot[w] = inc;
  __syncthreads();
  int add = 0;
  for (int i = 0; i < 4; ++i)
    if (i < w) add += wtot[i];
  int run = add + inc - sum;             // exclusive prefix for this chunk
  for (int j = 0; j < CH; ++j) {
    int idx = base + j;
    if (idx < NNODES) {
      int v = cnt[idx];
      row_start[idx] = run;
      cursor[idx] = run;
      run += v;
    }
  }
  if (t == 255) row_start[NNODES] = run;
}

// CSR fill with dinv folded in: packed[slot] = (src, -dinv_s*dinv_d), by dst.
__global__ void fill_kernel(const int* __restrict__ src, const int* __restrict__ dst,
                            const float* __restrict__ deg, int* __restrict__ cursor,
                            int2* __restrict__ packed) {
  int e = blockIdx.x * 256 + threadIdx.x;
  if (e >= NEDGES) return;
  int s = src[e], d = dst[e];
  if (s == d) return;
  float ds_ = deg[s], dd = deg[d];
  float dis = (ds_ > 0.f) ? 1.0f / sqrtf(ds_) : 0.f;
  float did = (dd  > 0.f) ? 1.0f / sqrtf(dd)  : 0.f;
  float w = -dis * did;
  int slot = atomicAdd(&cursor[d], 1);
  packed[slot] = make_int2(s, __float_as_int(w));
}

// ---------------------------------------------------------------------------
// Gather prop (atomic-free): one 16-lane group per node (mean in-degree 32).
//   tout[i,:] = scale * sum_{in-edges} w_e * tin[src_e,:]  - sub[i,:]
// sub==nullptr for Tx1 = P(Tx0); else fused Chebyshev Tx2 = 2*P(Tx1) - Tx0.
// ---------------------------------------------------------------------------
__global__ __launch_bounds__(256) void gather_kernel(
    const int* __restrict__ row_start, const int2* __restrict__ packed,
    const float* __restrict__ tin, const float* __restrict__ sub,
    float* __restrict__ tout, float scale) {
  const int g    = (blockIdx.x * 256 + threadIdx.x) >> 4;  // node id
  const int lane = threadIdx.x & 15;
  if (g >= NNODES) return;
  const int s0 = row_start[g], s1 = row_start[g + 1];
  float acc[NC];
#pragma unroll
  for (int c = 0; c < NC; ++c) acc[c] = 0.f;
  for (int j = s0 + lane; j < s1; j += 16) {
    int2 p = packed[j];
    float w = __int_as_float(p.y);
    const float2* t2 = (const float2*)(tin + (size_t)p.x * NC);  // 8B-aligned
    float2 a0 = t2[0], a1 = t2[1], a2 = t2[2], a3 = t2[3], a4 = t2[4];
    acc[0] = fmaf(w, a0.x, acc[0]); acc[1] = fmaf(w, a0.y, acc[1]);
    acc[2] = fmaf(w, a1.x, acc[2]); acc[3] = fmaf(w, a1.y, acc[3]);
    acc[4] = fmaf(w, a2.x, acc[4]); acc[5] = fmaf(w, a2.y, acc[5]);
    acc[6] = fmaf(w, a3.x, acc[6]); acc[7] = fmaf(w, a3.y, acc[7]);
    acc[8] = fmaf(w, a4.x, acc[8]); acc[9] = fmaf(w, a4.y, acc[9]);
  }
#pragma unroll
  for (int c = 0; c < NC; ++c) {       // reduce within the 16-lane group
    float v = acc[c];
#pragma unroll
    for (int off = 8; off > 0; off >>= 1) v += __shfl_xor(v, off);
    acc[c] = v;
  }
  if (lane == 0) {
    float* to = tout + (size_t)g * NC;
    if (sub) {
      const float* sb = sub + (size_t)g * NC;
#pragma unroll
      for (int c = 0; c < NC; ++c) to[c] = fmaf(scale, acc[c], -sb[c]);
    } else {
#pragma unroll
      for (int c = 0; c < NC; ++c) to[c] = scale * acc[c];
    }
  }
}

// ---------------------------------------------------------------------------
// Last gather (step 10) fused with proj: after the reduce every lane holds the
// fresh Tx10 row; lanes k=0..10 then compute e_k[node] (lane 10 from registers,
// others reading L2-hot Tx_k rows) and write Emat[(k,node)] directly.
// ---------------------------------------------------------------------------
__global__ __launch_bounds__(256) void gather_proj_kernel(
    const int* __restrict__ row_start, const int2* __restrict__ packed,
    const float* __restrict__ Txall, const float* __restrict__ Wp,
    const float* __restrict__ bp, const float* __restrict__ gamma,
    float* __restrict__ Emat) {
  const int g    = (blockIdx.x * 256 + threadIdx.x) >> 4;  // node id
  const int lane = threadIdx.x & 15;
  if (g >= NNODES) return;
  const float* tin = Txall + (size_t)(KHOP - 1) * NNODES * NC;  // Tx9
  const float* sub = Txall + (size_t)(KHOP - 2) * NNODES * NC;  // Tx8
  float*       tout = (float*)Txall + (size_t)KHOP * NNODES * NC; // Tx10

  const int s0 = row_start[g], s1 = row_start[g + 1];
  float acc[NC];
#pragma unroll
  for (int c = 0; c < NC; ++c) acc[c] = 0.f;
  for (int j = s0 + lane; j < s1; j += 16) {
    int2 p = packed[j];
    float w = __int_as_float(p.y);
    const float2* t2 = (const float2*)(tin + (size_t)p.x * NC);
    float2 a0 = t2[0], a1 = t2[1], a2 = t2[2], a3 = t2[3], a4 = t2[4];
    acc[0] = fmaf(w, a0.x, acc[0]); acc[1] = fmaf(w, a0.y, acc[1]);
    acc[2] = fmaf(w, a1.x, acc[2]); acc[3] = fmaf(w, a1.y, acc[3]);
    acc[4] = fmaf(w, a2.x, acc[4]); acc[5] = fmaf(w, a2.y, acc[5]);
    acc[6] = fmaf(w, a3.x, acc[6]); acc[7] = fmaf(w, a3.y, acc[7]);
    acc[8] = fmaf(w, a4.x, acc[8]); acc[9] = fmaf(w, a4.y, acc[9]);
  }
#pragma unroll
  for (int c = 0; c < NC; ++c) {       // butterfly: ALL 16 lanes get the sum
    float v = acc[c];
#pragma unroll
    for (int off = 8; off > 0; off >>= 1) v += __shfl_xor(v, off);
    acc[c] = v;
  }
  // Tx10 row in every lane's registers
  float r10[NC];
  const float* sb = sub + (size_t)g * NC;
#pragma unroll
  for (int c = 0; c < NC; ++c) r10[c] = fmaf(2.f, acc[c], -sb[c]);
  if (lane == 0) {
    float* to = tout + (size_t)g * NC;
#pragma unroll
    for (int c = 0; c < NC; ++c) to[c] = r10[c];
  }
  // proj: lane k handles Chebyshev order k (lanes 11..15 idle)
  if (lane < KP1) {
    const int k = lane;
    float tv[NC];
    if (k < KHOP) {
      const float* tx = Txall + ((size_t)k * NNODES + g) * NC;
#pragma unroll
      for (int c = 0; c < NC; ++c) tv[c] = tx[c];
    } else {
#pragma unroll
      for (int c = 0; c < NC; ++c) tv[c] = r10[c];
    }
    float e = 0.f;
#pragma unroll
    for (int r = 0; r < RANKP; ++r) {
      float hh = bp[k * RANKP + r];
#pragma unroll
      for (int c = 0; c < NC; ++c)
        hh = fmaf(tv[c], Wp[(k * NC + c) * RANKP + r], hh);
      e = fmaf(tanhf(hh), gamma[r * KP1 + k], e);
    }
    Emat[(size_t)k * NNODES + g] = e * (1.0f / RANKP);
  }
}

// ---------------------------------------------------------------------------
// etam(N,11) = CTC(N,N) @ E^T fused with final weighted-sum + log_softmax.
// 4 rows/block; reads CTC exactly once (400 MB -> the HBM-bound dispatch).
// Verified passing R7/R10.
// ---------------------------------------------------------------------------
__global__ __launch_bounds__(256) void gemv_final_kernel(
    const float* __restrict__ CTC, const float* __restrict__ Emat,
    const float* __restrict__ Txall, float* __restrict__ out) {
  const int i0 = blockIdx.x * 4;
  const int t = threadIdx.x;
  float acc[4][KP1];
#pragma unroll
  for (int r = 0; r < 4; ++r)
#pragma unroll
    for (int k = 0; k < KP1; ++k) acc[r][k] = 0.f;

  const int n4 = NNODES / 4;  // 2500 float4 per row
  for (int j4 = t; j4 < n4; j4 += 256) {
    float4 ev[KP1];
#pragma unroll
    for (int k = 0; k < KP1; ++k)
      ev[k] = ((const float4*)(Emat + (size_t)k * NNODES))[j4];
#pragma unroll
    for (int r = 0; r < 4; ++r) {
      float4 cv = ((const float4*)(CTC + (size_t)(i0 + r) * NNODES))[j4];
#pragma unroll
      for (int k = 0; k < KP1; ++k) {
        acc[r][k] = fmaf(cv.x, ev[k].x, acc[r][k]);
        acc[r][k] = fmaf(cv.y, ev[k].y, acc[r][k]);
        acc[r][k] = fmaf(cv.z, ev[k].z, acc[r][k]);
        acc[r][k] = fmaf(cv.w, ev[k].w, acc[r][k]);
      }
    }
  }

#pragma unroll
  for (int r = 0; r < 4; ++r)
#pragma unroll
    for (int k = 0; k < KP1; ++k) {
      float v = acc[r][k];
#pragma unroll
      for (int off = 32; off > 0; off >>= 1) v += __shfl_xor(v, off);
      acc[r][k] = v;
    }
  __shared__ float red[4][4 * KP1];
  const int w = t >> 6, lane = t & 63;
  if (lane == 0) {
#pragma unroll
    for (int r = 0; r < 4; ++r)
#pragma unroll
      for (int k = 0; k < KP1; ++k) red[w][r * KP1 + k] = acc[r][k];
  }
  __syncthreads();
  if (t < 4 * KP1) {                   // cross-wave sum -> etam in red[0][*]
    red[0][t] = red[0][t] + red[1][t] + red[2][t] + red[3][t];
  }
  __syncthreads();
  if (t < 4) {                         // fused final: per-node log_softmax
    const int node = i0 + t;
    float h[NC];
#pragma unroll
    for (int c = 0; c < NC; ++c) h[c] = 0.f;
    for (int k = 0; k < KP1; ++k) {
      const float e = red[0][t * KP1 + k];
      const float* tx = Txall + ((size_t)k * NNODES + node) * NC;
#pragma unroll
      for (int c = 0; c < NC; ++c) h[c] = fmaf(tx[c], e, h[c]);
    }
    float m = h[0];
#pragma unroll
    for (int c = 1; c < NC; ++c) m = fmaxf(m, h[c]);
    float s = 0.f;
#pragma unroll
    for (int c = 0; c < NC; ++c) s += expf(h[c] - m);
    const float ls = logf(s);
#pragma unroll
    for (int c = 0; c < NC; ++c) out[(size_t)node * NC + c] = h[c] - m - ls;
  }
}

// ---------------------------------------------------------------------------
extern "C" void kernel_launch(void* const* d_in, const int* in_sizes, int n_in,
                              void* d_out, int out_size, void* d_ws, size_t ws_size,
                              hipStream_t stream) {
  const float* feature = (const float*)d_in[0];
  const int*   edges   = (const int*)d_in[1];   // verified R3/R7/R10: int32
  const float* CTC     = (const float*)d_in[2];
  const float* W1      = (const float*)d_in[3];
  const float* b1      = (const float*)d_in[4];
  const float* W2      = (const float*)d_in[5];
  const float* b2      = (const float*)d_in[6];
  const float* gamma   = (const float*)d_in[7];
  const float* Wp      = (const float*)d_in[8];
  const float* bp      = (const float*)d_in[9];
  const int* src = edges;
  const int* dst = edges + NEDGES;
  float* out = (float*)d_out;

  // workspace carve-up (~9 MB; d_ws is 0xAA-poisoned before every call)
  float* ws        = (float*)d_ws;
  float* Txall     = ws;                                    // KP1*N*NC floats
  float* deg       = Txall + (size_t)KP1 * NNODES * NC;     // N floats
  int*   cnt       = (int*)(deg + NNODES);                  // N ints (zeroed w/ deg)
  int*   row_start = cnt + NNODES;                          // N+1 ints
  int*   cursor    = row_start + NNODES + 8;                // N ints
  int2*  packed    = (int2*)(cursor + NNODES + 8);          // E int2 (8B-aligned)
  float* Emat      = (float*)(packed + NEDGES);             // KP1*N floats

  const int GB = (NNODES * 16 + 255) / 256;       // 16-lane-group grids

  // zero deg (N floats) + cnt (N ints) in one memset — contiguous by layout
  hipMemsetAsync(deg, 0, 2 * NNODES * sizeof(float), stream);

  // MLP + degcnt fused (independent work, block-range split)
  mlp_degcnt_kernel<<<MLPB + EB, 256, 0, stream>>>(feature, W1, b1, W2, b2,
                                                   src, dst, Txall, deg, cnt);
  scan_kernel<<<1, 256, 0, stream>>>(cnt, row_start, cursor);
  fill_kernel<<<EB, 256, 0, stream>>>(src, dst, deg, cursor, packed);

  // Tx1 = P(Tx0); then Tx_{k+1} = 2*P(Tx_k) - Tx_{k-1}  (all atomic-free)
  float* Tx0 = Txall;
  float* Tx1 = Txall + (size_t)NNODES * NC;
  gather_kernel<<<GB, 256, 0, stream>>>(row_start, packed, Tx0, nullptr, Tx1, 1.0f);
  for (int k = 1; k < KHOP - 1; ++k) {
    float* prev = Txall + (size_t)(k - 1) * NNODES * NC;
    float* cur  = Txall + (size_t)k * NNODES * NC;
    float* nxt  = Txall + (size_t)(k + 1) * NNODES * NC;
    gather_kernel<<<GB, 256, 0, stream>>>(row_start, packed, cur, prev, nxt, 2.0f);
  }
  // last Chebyshev step fused with proj (writes Tx10 and all of Emat)
  gather_proj_kernel<<<GB, 256, 0, stream>>>(row_start, packed, Txall, Wp, bp,
                                             gamma, Emat);

  gemv_final_kernel<<<NNODES / 4, 256, 0, stream>>>(CTC, Emat, Txall, out);
}